// Round 1
// baseline (598.297 us; speedup 1.0000x reference)
//
#include <hip/hip_runtime.h>
#include <math.h>

#define N 8192
#define FIN 128
#define FOUT 64

// ---------------- Kernel A: h = x @ W  (8192x128 @ 128x64) ----------------
__global__ __launch_bounds__(256) void k_h(const float* __restrict__ x,
                                           const float* __restrict__ W,
                                           float* __restrict__ h) {
    __shared__ float Wl[FIN * FOUT];
    int t = threadIdx.x;
    // cooperative load of W (32 KB) into LDS, float4-coalesced
    #pragma unroll
    for (int i = 0; i < (FIN * FOUT) / (256 * 4); ++i) {
        int idx = (t + i * 256) * 4;
        *(float4*)&Wl[idx] = *(const float4*)&W[idx];
    }
    __syncthreads();
    int gid = blockIdx.x * 256 + t;
    int row = gid >> 6;
    int c   = gid & 63;
    float acc = 0.f;
    #pragma unroll
    for (int k = 0; k < FIN; k += 4) {
        float4 xv = *(const float4*)&x[row * FIN + k];   // uniform across wave -> broadcast
        acc = fmaf(xv.x, Wl[(k + 0) * FOUT + c], acc);
        acc = fmaf(xv.y, Wl[(k + 1) * FOUT + c], acc);
        acc = fmaf(xv.z, Wl[(k + 2) * FOUT + c], acc);
        acc = fmaf(xv.w, Wl[(k + 3) * FOUT + c], acc);
    }
    h[gid] = acc;
}

// ---------------- Kernel B: s1[r] = h[r,:].a1, s2[r] = h[r,:].a2 ----------------
__global__ __launch_bounds__(256) void k_s(const float* __restrict__ h,
                                           const float* __restrict__ a,
                                           float* __restrict__ s1,
                                           float* __restrict__ s2) {
    int wid  = (blockIdx.x * 256 + threadIdx.x) >> 6;   // one wave per row
    int lane = threadIdx.x & 63;
    float hv = h[wid * 64 + lane];
    float p1 = hv * a[lane];
    float p2 = hv * a[64 + lane];
    #pragma unroll
    for (int off = 32; off; off >>= 1) {
        p1 += __shfl_xor(p1, off);
        p2 += __shfl_xor(p2, off);
    }
    if (lane == 0) { s1[wid] = p1; s2[wid] = p2; }
}

// ---------------- Kernel C: S2MAX = max(s2) ----------------
__global__ __launch_bounds__(256) void k_max(const float* __restrict__ s2,
                                             float* __restrict__ s2max) {
    __shared__ float red[256];
    float m = -1e30f;
    for (int i = threadIdx.x; i < N; i += 256) m = fmaxf(m, s2[i]);
    red[threadIdx.x] = m;
    __syncthreads();
    #pragma unroll
    for (int s = 128; s; s >>= 1) {
        if (threadIdx.x < s) red[threadIdx.x] = fmaxf(red[threadIdx.x], red[threadIdx.x + s]);
        __syncthreads();
    }
    if (threadIdx.x == 0) *s2max = red[0];
}

// ---------------- Kernel D: masked softmax + attention @ h ----------------
// grid = 256 * JS blocks, 256 threads (4 waves). Each wave: 8 rows, lane = column.
// JS>1: write partial acc/den to ws; JS==1: finalize (div + elu) inline.
template <int JS>
__global__ __launch_bounds__(256, 4) void k_attn(const float* __restrict__ adj,
                                                 const float* __restrict__ h,
                                                 const float* __restrict__ s1,
                                                 const float* __restrict__ s2,
                                                 const float* __restrict__ s2max,
                                                 float* __restrict__ pacc,
                                                 float* __restrict__ pden,
                                                 float* __restrict__ out) {
    const int JLEN = N / JS;
    int wave = threadIdx.x >> 6;
    int lane = threadIdx.x & 63;
    int rb = blockIdx.x / JS;        // row-block [0,256)
    int js = blockIdx.x % JS;        // j segment
    int j_begin = js * JLEN;
    int r0 = rb * 32 + wave * 8;     // first of this wave's 8 rows

    __shared__ float wbuf[4][8][64];

    float acc[8], den[8], s1v[8], Mv[8];
    float S2M = *s2max;
    #pragma unroll
    for (int r = 0; r < 8; ++r) {
        acc[r] = 0.f; den[r] = 0.f;
        s1v[r] = s1[r0 + r];
        float p = s1v[r] + S2M;
        Mv[r] = fmaxf(p, 0.2f * p);  // lrelu(s1+max s2) >= any e in the row
    }

    for (int j0 = j_begin; j0 < j_begin + JLEN; j0 += 64) {
        float s2j = s2[j0 + lane];
        // phase 1: lanes <-> j ; compute attention weights for 8 rows x 64 j
        #pragma unroll
        for (int r = 0; r < 8; ++r) {
            float av  = __builtin_nontemporal_load(&adj[(r0 + r) * N + j0 + lane]);
            float pre = s1v[r] + s2j;
            float e   = fmaxf(pre, 0.2f * pre);          // leaky relu
            float w   = (av != 0.f) ? __expf(e - Mv[r]) : 0.f;
            den[r] += w;
            wbuf[wave][r][lane] = w;
        }
        // phase 2: lanes <-> columns ; acc[r][lane] += w[r][k] * h[j0+k][lane]
        #pragma unroll
        for (int k0 = 0; k0 < 64; k0 += 4) {
            float hk0 = h[(j0 + k0 + 0) * 64 + lane];
            float hk1 = h[(j0 + k0 + 1) * 64 + lane];
            float hk2 = h[(j0 + k0 + 2) * 64 + lane];
            float hk3 = h[(j0 + k0 + 3) * 64 + lane];
            #pragma unroll
            for (int r = 0; r < 8; ++r) {
                float4 w4 = *(float4*)&wbuf[wave][r][k0];  // uniform addr -> broadcast
                acc[r] = fmaf(w4.x, hk0, acc[r]);
                acc[r] = fmaf(w4.y, hk1, acc[r]);
                acc[r] = fmaf(w4.z, hk2, acc[r]);
                acc[r] = fmaf(w4.w, hk3, acc[r]);
            }
        }
    }

    // cross-lane sum of den
    #pragma unroll
    for (int r = 0; r < 8; ++r) {
        #pragma unroll
        for (int off = 32; off; off >>= 1) den[r] += __shfl_xor(den[r], off);
    }

    if (JS == 1) {
        #pragma unroll
        for (int r = 0; r < 8; ++r) {
            float v = acc[r] / den[r];
            out[(r0 + r) * 64 + lane] = v > 0.f ? v : expm1f(v);
        }
    } else {
        #pragma unroll
        for (int r = 0; r < 8; ++r) {
            pacc[((long)js * N + r0 + r) * 64 + lane] = acc[r];
            if (lane == 0) pden[js * N + r0 + r] = den[r];
        }
    }
}

// ---------------- Kernel E: combine partials, div + elu ----------------
template <int JS>
__global__ __launch_bounds__(256) void k_combine(const float* __restrict__ pacc,
                                                 const float* __restrict__ pden,
                                                 float* __restrict__ out) {
    int gid = blockIdx.x * 256 + threadIdx.x;   // [0, N*64)
    int row = gid >> 6;
    float a = 0.f, d = 0.f;
    #pragma unroll
    for (int s = 0; s < JS; ++s) {
        a += pacc[((long)s * N + row) * 64 + (gid & 63)];
        d += pden[s * N + row];
    }
    float v = a / d;
    out[gid] = v > 0.f ? v : expm1f(v);
}

// ---------------- launch ----------------
extern "C" void kernel_launch(void* const* d_in, const int* in_sizes, int n_in,
                              void* d_out, int out_size, void* d_ws, size_t ws_size,
                              hipStream_t stream) {
    const float* x   = (const float*)d_in[0];
    const float* adj = (const float*)d_in[1];
    const float* W   = (const float*)d_in[2];
    const float* a   = (const float*)d_in[3];
    float* out = (float*)d_out;

    // ws layout (floats)
    float* ws   = (float*)d_ws;
    float* h    = ws;                       // 524288 floats (2 MB)
    float* s1   = h + (size_t)N * FOUT;     // 8192
    float* s2   = s1 + N;                   // 8192
    float* s2m  = s2 + N;                   // 64 (padded)
    float* pden = s2m + 64;                 // 4*8192
    float* pacc = pden + 4 * N;             // 4*524288

    size_t need_js4 = (size_t)((pacc + 4 * (size_t)N * FOUT) - ws) * sizeof(float);
    int js = (ws_size >= need_js4) ? 4 : 1;

    k_h<<<dim3((N * FOUT) / 256), dim3(256), 0, stream>>>(x, W, h);
    k_s<<<dim3((N * 64) / 256), dim3(256), 0, stream>>>(h, a, s1, s2);
    k_max<<<dim3(1), dim3(256), 0, stream>>>(s2, s2m);

    if (js == 4) {
        k_attn<4><<<dim3(256 * 4), dim3(256), 0, stream>>>(adj, h, s1, s2, s2m, pacc, pden, out);
        k_combine<4><<<dim3((N * FOUT) / 256), dim3(256), 0, stream>>>(pacc, pden, out);
    } else {
        k_attn<1><<<dim3(256), dim3(256), 0, stream>>>(adj, h, s1, s2, s2m, pacc, pden, out);
    }
}

// Round 2
// 135.743 us; speedup vs baseline: 4.4076x; 4.4076x over previous
//
#include <hip/hip_runtime.h>
#include <math.h>

#define N 8192
#define FIN 128
#define FOUT 64
#define ALPHA 0.2f

typedef __attribute__((ext_vector_type(8))) short bf16x8;
typedef __attribute__((ext_vector_type(8))) unsigned short ushort8;
typedef __attribute__((ext_vector_type(4))) float f32x4;

__device__ __forceinline__ unsigned short f2bf(float f) {
    unsigned int u = __float_as_uint(f);
    u += 0x7fff + ((u >> 16) & 1);          // round-to-nearest-even
    return (unsigned short)(u >> 16);
}
__device__ __forceinline__ float elu(float v) { return v > 0.f ? v : expm1f(v); }

// ---------------- Kernel A: h = x @ W  (8192x128 @ 128x64) ----------------
__global__ __launch_bounds__(256) void k_h(const float* __restrict__ x,
                                           const float* __restrict__ W,
                                           float* __restrict__ h) {
    __shared__ float Wl[FIN * FOUT];
    int t = threadIdx.x;
    #pragma unroll
    for (int i = 0; i < (FIN * FOUT) / (256 * 4); ++i) {
        int idx = (t + i * 256) * 4;
        *(float4*)&Wl[idx] = *(const float4*)&W[idx];
    }
    __syncthreads();
    int gid = blockIdx.x * 256 + t;
    int row = gid >> 6;
    int c   = gid & 63;
    float acc = 0.f;
    #pragma unroll
    for (int k = 0; k < FIN; k += 4) {
        float4 xv = *(const float4*)&x[row * FIN + k];
        acc = fmaf(xv.x, Wl[(k + 0) * FOUT + c], acc);
        acc = fmaf(xv.y, Wl[(k + 1) * FOUT + c], acc);
        acc = fmaf(xv.z, Wl[(k + 2) * FOUT + c], acc);
        acc = fmaf(xv.w, Wl[(k + 3) * FOUT + c], acc);
    }
    h[gid] = acc;
}

// ---------------- Kernel B: s1[r] = h[r,:].a1, s2[r] = h[r,:].a2 ----------------
__global__ __launch_bounds__(256) void k_s(const float* __restrict__ h,
                                           const float* __restrict__ a,
                                           float* __restrict__ s1,
                                           float* __restrict__ s2) {
    int wid  = (blockIdx.x * 256 + threadIdx.x) >> 6;
    int lane = threadIdx.x & 63;
    float hv = h[wid * 64 + lane];
    float p1 = hv * a[lane];
    float p2 = hv * a[64 + lane];
    #pragma unroll
    for (int off = 32; off; off >>= 1) {
        p1 += __shfl_xor(p1, off);
        p2 += __shfl_xor(p2, off);
    }
    if (lane == 0) { s1[wid] = p1; s2[wid] = p2; }
}

// ---------------- Kernel C: S2MAX = max(s2) ----------------
__global__ __launch_bounds__(256) void k_max(const float* __restrict__ s2,
                                             float* __restrict__ s2max) {
    __shared__ float red[256];
    float m = -1e30f;
    for (int i = threadIdx.x; i < N; i += 256) m = fmaxf(m, s2[i]);
    red[threadIdx.x] = m;
    __syncthreads();
    #pragma unroll
    for (int s = 128; s; s >>= 1) {
        if (threadIdx.x < s) red[threadIdx.x] = fmaxf(red[threadIdx.x], red[threadIdx.x + s]);
        __syncthreads();
    }
    if (threadIdx.x == 0) *s2max = red[0];
}

// ---------------- Kernel T: hT[c][j] = bf16(h[j][c])  (64 x 8192) ----------------
__global__ __launch_bounds__(256) void k_t(const float* __restrict__ h,
                                           unsigned short* __restrict__ hT) {
    __shared__ float tile[64][65];
    int t = threadIdx.x;
    int j0 = blockIdx.x * 64;
    #pragma unroll
    for (int p = 0; p < 4; ++p) {
        int j = p * 16 + (t >> 4);
        int c4 = (t & 15) * 4;
        float4 v = *(const float4*)&h[(size_t)(j0 + j) * 64 + c4];
        tile[j][c4] = v.x; tile[j][c4 + 1] = v.y; tile[j][c4 + 2] = v.z; tile[j][c4 + 3] = v.w;
    }
    __syncthreads();
    int c = t & 63, seg = t >> 6;       // 4 segments of 16 j each
    ushort8 u0, u1;
    #pragma unroll
    for (int k = 0; k < 8; ++k) u0[k] = f2bf(tile[seg * 16 + k][c]);
    #pragma unroll
    for (int k = 0; k < 8; ++k) u1[k] = f2bf(tile[seg * 16 + 8 + k][c]);
    unsigned short* dst = &hT[(size_t)c * N + j0 + seg * 16];
    *(ushort8*)dst = u0;
    *(ushort8*)(dst + 8) = u1;
}

// ---------------- Kernel D: masked softmax + attention @ h via MFMA ----------------
// 1 wave = 16 output rows x 64 cols. Lane l computes A-fragment elements
// w[l&15][(l>>4)*8 + i] directly (matches mfma_f32_16x16x32_bf16 A layout).
// B fragment = 16B contiguous load from bf16 hT. No LDS, no barriers.
template <int JS>
__global__ __launch_bounds__(256, 4) void k_attn(const float* __restrict__ adj,
                                                 const unsigned short* __restrict__ hT,
                                                 const float* __restrict__ s1,
                                                 const float* __restrict__ s2,
                                                 const float* __restrict__ s2max,
                                                 float* __restrict__ pacc,
                                                 float* __restrict__ pden,
                                                 float* __restrict__ out) {
    int wave = threadIdx.x >> 6;
    int lane = threadIdx.x & 63;
    int rt   = (blockIdx.x / JS) * 4 + wave;   // row tile [0, 512)
    int js   = blockIdx.x % JS;
    int r0   = rt * 16;
    const int JLEN = N / JS;
    int jb   = js * JLEN;

    int row = lane & 15;    // A row within tile; also B column within col-tile
    int kg  = lane >> 4;    // k-group: this lane's 8 contiguous k
    int r   = r0 + row;

    float s1v = s1[r];
    float S2M = *s2max;
    float pM  = s1v + S2M;
    float Mv  = fmaxf(pM, ALPHA * pM);  // lrelu monotone: >= any e in row

    f32x4 acc0 = {0.f, 0.f, 0.f, 0.f};
    f32x4 acc1 = {0.f, 0.f, 0.f, 0.f};
    f32x4 acc2 = {0.f, 0.f, 0.f, 0.f};
    f32x4 acc3 = {0.f, 0.f, 0.f, 0.f};
    float den = 0.f;

    const size_t rbase = (size_t)r * N;
    for (int j0 = jb; j0 < jb + JLEN; j0 += 32) {
        int jj = j0 + kg * 8;
        float4 a0 = *(const float4*)&adj[rbase + jj];
        float4 a1 = *(const float4*)&adj[rbase + jj + 4];
        float4 t0 = *(const float4*)&s2[jj];
        float4 t1 = *(const float4*)&s2[jj + 4];

        float av[8] = {a0.x, a0.y, a0.z, a0.w, a1.x, a1.y, a1.z, a1.w};
        float sv[8] = {t0.x, t0.y, t0.z, t0.w, t1.x, t1.y, t1.z, t1.w};

        union { bf16x8 v; unsigned short u[8]; } af;
        #pragma unroll
        for (int i = 0; i < 8; ++i) {
            float pre = s1v + sv[i];
            float e   = fmaxf(pre, ALPHA * pre);
            float w   = (av[i] != 0.f) ? __expf(e - Mv) : 0.f;
            den += w;
            af.u[i] = f2bf(w);
        }

        bf16x8 b0 = *(const bf16x8*)&hT[(size_t)(0 * 16 + row) * N + jj];
        bf16x8 b1 = *(const bf16x8*)&hT[(size_t)(1 * 16 + row) * N + jj];
        bf16x8 b2 = *(const bf16x8*)&hT[(size_t)(2 * 16 + row) * N + jj];
        bf16x8 b3 = *(const bf16x8*)&hT[(size_t)(3 * 16 + row) * N + jj];
        acc0 = __builtin_amdgcn_mfma_f32_16x16x32_bf16(af.v, b0, acc0, 0, 0, 0);
        acc1 = __builtin_amdgcn_mfma_f32_16x16x32_bf16(af.v, b1, acc1, 0, 0, 0);
        acc2 = __builtin_amdgcn_mfma_f32_16x16x32_bf16(af.v, b2, acc2, 0, 0, 0);
        acc3 = __builtin_amdgcn_mfma_f32_16x16x32_bf16(af.v, b3, acc3, 0, 0, 0);
    }

    // den: sum lanes {row, row+16, row+32, row+48} -> every lane has den[lane&15]
    den += __shfl_xor(den, 16);
    den += __shfl_xor(den, 32);

    #pragma unroll
    for (int q = 0; q < 4; ++q) {
        int ro = kg * 4 + q;               // D row within tile
        float d = __shfl(den, ro);
        float v0 = acc0[q], v1 = acc1[q], v2 = acc2[q], v3 = acc3[q];
        if (JS == 1) {
            size_t ob = (size_t)(r0 + ro) * 64 + row;
            out[ob + 0]  = elu(v0 / d);
            out[ob + 16] = elu(v1 / d);
            out[ob + 32] = elu(v2 / d);
            out[ob + 48] = elu(v3 / d);
        } else {
            size_t ob = ((size_t)js * N + r0 + ro) * 64 + row;
            pacc[ob + 0]  = v0;
            pacc[ob + 16] = v1;
            pacc[ob + 32] = v2;
            pacc[ob + 48] = v3;
        }
    }
    if (JS > 1 && lane < 16) pden[(size_t)js * N + r0 + lane] = den;
}

// ---------------- Kernel E: combine partials, div + elu ----------------
template <int JS>
__global__ __launch_bounds__(256) void k_combine(const float* __restrict__ pacc,
                                                 const float* __restrict__ pden,
                                                 float* __restrict__ out) {
    int gid = blockIdx.x * 256 + threadIdx.x;   // [0, N*64)
    int row = gid >> 6;
    float a = 0.f, d = 0.f;
    #pragma unroll
    for (int s = 0; s < JS; ++s) {
        a += pacc[((size_t)s * N + row) * 64 + (gid & 63)];
        d += pden[(size_t)s * N + row];
    }
    out[gid] = elu(a / d);
}

// ---------------- launch ----------------
extern "C" void kernel_launch(void* const* d_in, const int* in_sizes, int n_in,
                              void* d_out, int out_size, void* d_ws, size_t ws_size,
                              hipStream_t stream) {
    const float* x   = (const float*)d_in[0];
    const float* adj = (const float*)d_in[1];
    const float* W   = (const float*)d_in[2];
    const float* a   = (const float*)d_in[3];
    float* out = (float*)d_out;

    // ws layout (floats)
    float* ws   = (float*)d_ws;
    float* h    = ws;                              // 524288
    float* s1   = h + (size_t)N * FOUT;            // 8192
    float* s2   = s1 + N;                          // 8192
    float* s2m  = s2 + N;                          // 64
    float* pden = s2m + 64;                        // 8*8192 (max JS)
    unsigned short* hT = (unsigned short*)(pden + 8 * N);  // 64*8192 ushorts = 262144 floats
    float* pacc = (float*)hT + 262144;             // JS*524288

    size_t fixed = 524288 + 8192 + 8192 + 64 + 8 * N + 262144;
    int js = 1;
    if (ws_size >= (fixed + 8 * 524288ull) * 4) js = 8;
    else if (ws_size >= (fixed + 4 * 524288ull) * 4) js = 4;
    else if (ws_size >= (fixed + 2 * 524288ull) * 4) js = 2;

    k_h<<<dim3((N * FOUT) / 256), dim3(256), 0, stream>>>(x, W, h);
    k_s<<<dim3((N * 64) / 256), dim3(256), 0, stream>>>(h, a, s1, s2);
    k_max<<<dim3(1), dim3(256), 0, stream>>>(s2, s2m);
    k_t<<<dim3(N / 64), dim3(256), 0, stream>>>(h, hT);

    switch (js) {
        case 8:
            k_attn<8><<<dim3(128 * 8), dim3(256), 0, stream>>>(adj, hT, s1, s2, s2m, pacc, pden, out);
            k_combine<8><<<dim3((N * FOUT) / 256), dim3(256), 0, stream>>>(pacc, pden, out);
            break;
        case 4:
            k_attn<4><<<dim3(128 * 4), dim3(256), 0, stream>>>(adj, hT, s1, s2, s2m, pacc, pden, out);
            k_combine<4><<<dim3((N * FOUT) / 256), dim3(256), 0, stream>>>(pacc, pden, out);
            break;
        case 2:
            k_attn<2><<<dim3(128 * 2), dim3(256), 0, stream>>>(adj, hT, s1, s2, s2m, pacc, pden, out);
            k_combine<2><<<dim3((N * FOUT) / 256), dim3(256), 0, stream>>>(pacc, pden, out);
            break;
        default:
            k_attn<1><<<dim3(128), dim3(256), 0, stream>>>(adj, hT, s1, s2, s2m, pacc, pden, out);
            break;
    }
}